// Round 2
// baseline (161.208 us; speedup 1.0000x reference)
//
#include <hip/hip_runtime.h>

// PercolationQ: per-patch occupancy fraction -> threshold -> mean over patches.
// x4:  [3,64,4096, 4, 4]  patch = 16 floats  =  64 B ; 786432 patches
// x8:  [3,64,1024, 8, 8]  patch = 64 floats  = 256 B ; 196608 patches
// x16: [3,64, 256,16,16]  patch = 256 floats =   4 KB;  49152 patches
// One THREAD per patch: contiguous per-thread float4 reads, zero cross-lane
// ops for the patch sum (predicate -> ballot/popc once per wave).
// out: 576 floats = [q4(192) | q8(192) | q16(192)], row-major [c*64+b].
//
// Block layout (1-D grid, heavy blocks first so they dispatch early):
//   [0,192)    : x16, 256 patches/block, row = bx          (256 patches/row)
//   [192,960)  : x8,  256 patches/block, row = (bx-192)>>2 (1024 patches/row)
//   [960,4032) : x4,  256 patches/block, row = (bx-960)>>4 (4096 patches/row)

#define PERC_THRESHOLD 0.59275f

// Sum NV float4s starting at xv[base] with 4 independent accumulator chains.
template <int NV>
__device__ __forceinline__ float patch_sum(const float4* __restrict__ xv, int base) {
    float s0 = 0.f, s1 = 0.f, s2 = 0.f, s3 = 0.f;
#pragma unroll
    for (int k = 0; k < NV; k += 4) {
        float4 a = xv[base + k + 0];
        float4 b = xv[base + k + 1];
        float4 c = xv[base + k + 2];
        float4 d = xv[base + k + 3];
        s0 += (a.x + a.y) + (a.z + a.w);
        s1 += (b.x + b.y) + (b.z + b.w);
        s2 += (c.x + c.y) + (c.z + c.w);
        s3 += (d.x + d.y) + (d.z + d.w);
    }
    return (s0 + s1) + (s2 + s3);
}

__global__ __launch_bounds__(256)
void PercolationQ_31885837205970_kernel(const float* __restrict__ x4,
                                        const float* __restrict__ x8,
                                        const float* __restrict__ x16,
                                        float* __restrict__ out) {
    const int bx = blockIdx.x;
    const int tid = threadIdx.x;

    bool pred;
    int row;
    float invP;
    float* o;

    if (bx < 192) {                       // B = 16
        const float4* xv = (const float4*)x16;
        int base = (bx * 256 + tid) * 64;
        float s = patch_sum<64>(xv, base);
        pred = s * (1.0f / 256.0f) >= PERC_THRESHOLD;   // /256 exact (pow2)
        row = bx; invP = 1.0f / 256.0f; o = out + 384;
    } else if (bx < 960) {                // B = 8
        const float4* xv = (const float4*)x8;
        int b = bx - 192;
        int base = (b * 256 + tid) * 16;
        float s = patch_sum<16>(xv, base);
        pred = s * (1.0f / 64.0f) >= PERC_THRESHOLD;    // /64 exact
        row = b >> 2; invP = 1.0f / 1024.0f; o = out + 192;
    } else {                              // B = 4
        const float4* xv = (const float4*)x4;
        int b = bx - 960;
        int base = (b * 256 + tid) * 4;
        float s = patch_sum<4>(xv, base);
        pred = s * (1.0f / 16.0f) >= PERC_THRESHOLD;    // /16 exact
        row = b >> 4; invP = 1.0f / 4096.0f; o = out;
    }

    // one patch per thread -> per-wave count is just ballot+popc
    unsigned long long m = __ballot(pred);
    int cnt = __popcll(m);

    __shared__ int wsum[4];
    if ((tid & 63) == 0) wsum[tid >> 6] = cnt;
    __syncthreads();
    if (tid == 0) {
        float total = (float)(wsum[0] + wsum[1] + wsum[2] + wsum[3]);
        atomicAdd(&o[row], total * invP);  // invP is 2^-k -> exact scaling
    }
}

extern "C" void kernel_launch(void* const* d_in, const int* in_sizes, int n_in,
                              void* d_out, int out_size, void* d_ws, size_t ws_size,
                              hipStream_t stream) {
    const float* x4  = (const float*)d_in[0];
    const float* x8  = (const float*)d_in[1];
    const float* x16 = (const float*)d_in[2];
    float* out = (float*)d_out;

    // d_out is re-poisoned to 0xAA before every launch; we accumulate via atomics.
    hipMemsetAsync(d_out, 0, (size_t)out_size * sizeof(float), stream);

    dim3 grid(4032), block(256);
    hipLaunchKernelGGL(PercolationQ_31885837205970_kernel, grid, block, 0, stream,
                       x4, x8, x16, out);
}